// Round 12
// baseline (2299.735 us; speedup 1.0000x reference)
//
#include <hip/hip_runtime.h>
#include <hip/hip_bf16.h>
#include <math.h>

typedef __hip_bfloat16 bf16;

#define EMB 12
#define NCLS 17
#define NG 1000
#define BSHIFT 9
#define BSPAN 512            // cols per bucket
#define MAXNB 1024           // max buckets (N <= 524287)
#define CHUNK 16384          // edges per block (16384 beats 4096: r7/r8 A/B)
#define EB 8                 // edge batch (MLP) in count/place
#define ASTR 13              // LDS acc stride (13 coprime 32 -> no bank clustering)

__device__ __forceinline__ float b2f(bf16 v){ return __bfloat162float(v); }

__device__ __forceinline__ unsigned short f2bf_rne(float f){
  unsigned int u = __float_as_uint(f);
  unsigned int r = (u + 0x7FFFu + ((u >> 16) & 1u)) >> 16;
  return (unsigned short)r;
}

__device__ __forceinline__ float ldf(const void* p, size_t i, int isbf){
  if (isbf) return b2f(((const bf16*)p)[i]);
  return ((const float*)p)[i];
}
__device__ __forceinline__ void stout(void* p, size_t i, float v, int isbf){
  if (isbf) ((unsigned short*)p)[i] = f2bf_rne(v);
  else      ((float*)p)[i] = v;
}

// ---- row load/store, stride 16 elements ----------------------------------
__device__ __forceinline__ void rowload(const float* p, float o[12]){
  const float4* q = (const float4*)p;
  float4 a = q[0], b = q[1], c = q[2];
  o[0]=a.x;o[1]=a.y;o[2]=a.z;o[3]=a.w;o[4]=b.x;o[5]=b.y;o[6]=b.z;o[7]=b.w;
  o[8]=c.x;o[9]=c.y;o[10]=c.z;o[11]=c.w;
}
__device__ __forceinline__ void rowload(const bf16* p, float o[12]){
  const uint4* q = (const uint4*)p;       // 32B row, 16B aligned
  uint4 u0 = q[0];
  uint2 u1 = *(const uint2*)(q+1);
  o[0] =__uint_as_float(u0.x<<16); o[1] =__uint_as_float(u0.x&0xFFFF0000u);
  o[2] =__uint_as_float(u0.y<<16); o[3] =__uint_as_float(u0.y&0xFFFF0000u);
  o[4] =__uint_as_float(u0.z<<16); o[5] =__uint_as_float(u0.z&0xFFFF0000u);
  o[6] =__uint_as_float(u0.w<<16); o[7] =__uint_as_float(u0.w&0xFFFF0000u);
  o[8] =__uint_as_float(u1.x<<16); o[9] =__uint_as_float(u1.x&0xFFFF0000u);
  o[10]=__uint_as_float(u1.y<<16); o[11]=__uint_as_float(u1.y&0xFFFF0000u);
}
__device__ __forceinline__ void rowstore(float* p, const float o[12]){
  float4* q = (float4*)p;
  q[0] = make_float4(o[0],o[1],o[2],o[3]);
  q[1] = make_float4(o[4],o[5],o[6],o[7]);
  q[2] = make_float4(o[8],o[9],o[10],o[11]);
}
__device__ __forceinline__ void rowstore(bf16* p, const float o[12]){
  unsigned int u[6];
  #pragma unroll
  for (int k=0;k<6;k++)
    u[k] = (unsigned int)f2bf_rne(o[2*k]) | ((unsigned int)f2bf_rne(o[2*k+1])<<16);
  uint2* q = (uint2*)p;
  q[0] = make_uint2(u[0],u[1]);
  q[1] = make_uint2(u[2],u[3]);
  q[2] = make_uint2(u[4],u[5]);
}

// ---- runtime dtype detection ---------------------------------------------
__global__ void k_detect(const int* __restrict__ ei, const unsigned short* __restrict__ xh,
                         int* __restrict__ flags){
  if (blockIdx.x==0 && threadIdx.x==0){
    int z = 1;
    for (int k=1; k<32; k+=2) z &= (ei[k]==0);
    flags[0] = z;
    int hits = 0;
    for (int k=0; k<32; k+=2){
      int e = (xh[k] >> 7) & 0xFF;
      if (e >= 100 && e <= 140) hits++;
    }
    flags[1] = (hits >= 12) ? 1 : 0;
  }
}
__device__ __forceinline__ int ld_row(const int* ei, long long E, long long i, int w64){
  return w64 ? ei[2*i] : ei[i];
}
__device__ __forceinline__ int ld_col(const int* ei, long long E, long long i, int w64){
  return w64 ? ei[2*E + 2*i] : ei[E + i];
}
__device__ __forceinline__ int ld_batch(const int* b, long long i, int w64){
  return w64 ? b[2*i] : b[i];
}

// ---- bucketed edge partition (no per-edge global atomics) ----------------
__global__ void k_zero_i(int* __restrict__ p, int n){
  int i = blockIdx.x*blockDim.x + threadIdx.x;
  if (i < n) p[i] = 0;
}
__global__ void __launch_bounds__(256)
k_bkt_count(const int* __restrict__ ei, const int* __restrict__ flags,
            int* __restrict__ bcnt, int E, int NB){
  __shared__ int h[MAXNB];
  int t = threadIdx.x;
  for (int j=t; j<NB; j+=256) h[j] = 0;
  __syncthreads();
  int w64 = flags[0];
  long long base = (long long)blockIdx.x * CHUNK;
  for (int k0=0; k0<CHUNK; k0+=256*EB){
    int c[EB]; bool v[EB];
    #pragma unroll
    for (int u=0;u<EB;u++){
      long long i = base + k0 + u*256 + t;
      v[u] = (i < E);
      c[u] = v[u] ? ld_col(ei, E, i, w64) : 0;
    }
    #pragma unroll
    for (int u=0;u<EB;u++) if (v[u]) atomicAdd(&h[c[u]>>BSHIFT], 1);
  }
  __syncthreads();
  for (int j=t; j<NB; j+=256){
    int c = h[j];
    if (c > 0) atomicAdd(&bcnt[j], c);
  }
}
__global__ void __launch_bounds__(1024)
k_bkt_scan_par(const int* __restrict__ bcnt, int* __restrict__ bbase,
               int* __restrict__ bcursor, int NB){
  __shared__ int s[1024];
  int t = threadIdx.x;
  int v = (t < NB) ? bcnt[t] : 0;
  s[t] = v;
  __syncthreads();
  for (int off=1; off<1024; off<<=1){
    int add = (t >= off) ? s[t-off] : 0;
    __syncthreads();
    s[t] += add;
    __syncthreads();
  }
  if (t < NB){
    int excl = s[t] - v;
    bbase[t]   = excl;
    bcursor[t] = excl;
  }
  if (t == 1023) bbase[NB] = s[1023];
}
// Pass C: place packed (coloff<<19 | row), 8-edge batched.
__global__ void __launch_bounds__(256)
k_bkt_place(const int* __restrict__ ei, const int* __restrict__ flags,
            int* __restrict__ bcursor, int* __restrict__ pairs, int E, int NB){
  __shared__ int h[MAXNB];
  int t = threadIdx.x;
  for (int j=t; j<NB; j+=256) h[j] = 0;
  __syncthreads();
  int w64 = flags[0];
  long long base = (long long)blockIdx.x * CHUNK;
  for (int k0=0; k0<CHUNK; k0+=256*EB){
    int c[EB]; bool v[EB];
    #pragma unroll
    for (int u=0;u<EB;u++){
      long long i = base + k0 + u*256 + t;
      v[u] = (i < E);
      c[u] = v[u] ? ld_col(ei, E, i, w64) : 0;
    }
    #pragma unroll
    for (int u=0;u<EB;u++) if (v[u]) atomicAdd(&h[c[u]>>BSHIFT], 1);
  }
  __syncthreads();
  for (int j=t; j<NB; j+=256){
    int c = h[j];
    h[j] = (c > 0) ? atomicAdd(&bcursor[j], c) : 0;
  }
  __syncthreads();
  for (int k0=0; k0<CHUNK; k0+=256*EB){
    int r[EB], c[EB]; bool v[EB];
    #pragma unroll
    for (int u=0;u<EB;u++){
      long long i = base + k0 + u*256 + t;
      v[u] = (i < E);
      r[u] = v[u] ? ld_row(ei, E, i, w64) : 0;
      c[u] = v[u] ? ld_col(ei, E, i, w64) : 0;
    }
    int pos[EB];
    #pragma unroll
    for (int u=0;u<EB;u++) pos[u] = v[u] ? atomicAdd(&h[c[u]>>BSHIFT], 1) : 0;
    #pragma unroll
    for (int u=0;u<EB;u++)
      if (v[u]) pairs[pos[u]] = r[u] | ((c[u] & (BSPAN-1)) << 19);
  }
}
// Pass D: per-col degree -> dinv (one block per bucket, streaming pairs)
__global__ void __launch_bounds__(256)
k_deg(const int* __restrict__ pairs, const int* __restrict__ bbase,
      float* __restrict__ dinv, int N){
  __shared__ int cnt[BSPAN];
  int b = blockIdx.x, t = threadIdx.x;
  int lo = bbase[b], hi = bbase[b+1];
  cnt[2*t] = 0; cnt[2*t+1] = 0;
  __syncthreads();
  int p = lo + t;
  for (; p + 3*256 < hi; p += 4*256){
    int k0=pairs[p]>>19, k1=pairs[p+256]>>19, k2=pairs[p+512]>>19, k3=pairs[p+768]>>19;
    atomicAdd(&cnt[k0],1); atomicAdd(&cnt[k1],1);
    atomicAdd(&cnt[k2],1); atomicAdd(&cnt[k3],1);
  }
  for (; p < hi; p += 256) atomicAdd(&cnt[pairs[p]>>19],1);
  __syncthreads();
  int col0 = b << BSHIFT;
  #pragma unroll
  for (int u=0;u<2;u++){
    int j = 2*t + u;
    int col = col0 + j;
    if (col < N) dinv[col] = rsqrtf((float)cnt[j] + 1.0f);
  }
}

// ---- lin-first: g = dinv * (x @ W0 + b0), row stride 16 ------------------
template<typename GT>
__global__ void k_lin_first(const void* __restrict__ x, const void* __restrict__ W,
                            const void* __restrict__ b, const int* __restrict__ flags,
                            const float* __restrict__ dinv,
                            GT* __restrict__ g, int n){
  __shared__ float Ws[4*EMB];
  __shared__ float bs[EMB];
  int t = threadIdx.x;
  int isbf = flags[1];
  if (t < 4*EMB) Ws[t] = ldf(W, t, isbf);
  if (t < EMB)   bs[t] = ldf(b, t, isbf);
  __syncthreads();
  int i = blockIdx.x*blockDim.x + t;
  if (i >= n) return;
  float xi[4];
  #pragma unroll
  for (int k=0;k<4;k++) xi[k] = ldf(x, (size_t)i*4+k, isbf);
  float d = dinv[i];
  float o[12];
  #pragma unroll
  for (int j=0;j<EMB;j++){
    float h = bs[j];
    #pragma unroll
    for (int k=0;k<4;k++) h = fmaf(xi[k], Ws[k*EMB+j], h);
    o[j] = d*h;
  }
  rowstore(g + (size_t)i*16, o);
}

// ---- edge-parallel fused aggregation: one block per bucket ---------------
// acc[512][12] in LDS (stride 13); uniform edges/thread; epilogue does
// self-term + tanh + 12x12 GEMM (+dinv scale) or final tanh->acc.
__device__ __forceinline__ void lds_acc12(float* a, const float h[12]){
  #pragma unroll
  for (int j=0;j<12;j++) atomicAdd(a+j, h[j]);
}

template<typename GT, int LAST>
__global__ void __launch_bounds__(256)
k_agg(const int* __restrict__ pairs, const int* __restrict__ bbase,
      const float* __restrict__ dinv, const GT* __restrict__ gin,
      const void* __restrict__ W, const void* __restrict__ b,
      const int* __restrict__ flags, GT* __restrict__ gout,
      float* __restrict__ acc, int N){
  __shared__ float accL[BSPAN*ASTR];   // 26.6 KB
  __shared__ float Ws[EMB*EMB];
  __shared__ float bs[EMB];
  int t = threadIdx.x, bkt = blockIdx.x;
  int isbf = flags[1];
  if (!LAST){
    if (t < EMB*EMB) Ws[t] = ldf(W, t, isbf);
    if (t < EMB)     bs[t] = ldf(b, t, isbf);
  }
  for (int j=t; j<BSPAN*ASTR; j+=256) accL[j] = 0.f;
  __syncthreads();
  int lo = bbase[bkt], hi = bbase[bkt+1];
  int p = lo + t;
  for (; p + 3*256 < hi; p += 4*256){
    int pk0=pairs[p], pk1=pairs[p+256], pk2=pairs[p+512], pk3=pairs[p+768];
    float h0[12], h1[12], h2[12], h3[12];
    rowload(gin + (size_t)(pk0 & 0x7FFFF)*16, h0);
    rowload(gin + (size_t)(pk1 & 0x7FFFF)*16, h1);
    rowload(gin + (size_t)(pk2 & 0x7FFFF)*16, h2);
    rowload(gin + (size_t)(pk3 & 0x7FFFF)*16, h3);
    lds_acc12(&accL[(pk0>>19)*ASTR], h0);
    lds_acc12(&accL[(pk1>>19)*ASTR], h1);
    lds_acc12(&accL[(pk2>>19)*ASTR], h2);
    lds_acc12(&accL[(pk3>>19)*ASTR], h3);
  }
  for (; p < hi; p += 256){
    int pk = pairs[p];
    float h[12];
    rowload(gin + (size_t)(pk & 0x7FFFF)*16, h);
    lds_acc12(&accL[(pk>>19)*ASTR], h);
  }
  __syncthreads();
  int col0 = bkt << BSHIFT;
  #pragma unroll
  for (int u=0;u<2;u++){
    int j = 2*t + u;
    int col = col0 + j;
    if (col >= N) continue;
    float a[12];
    rowload(gin + (size_t)col*16, a);         // self-loop term
    #pragma unroll
    for (int k=0;k<12;k++) a[k] += accL[j*ASTR + k];
    float d = dinv[col];
    if (LAST){
      float4* ap = (float4*)(acc + (size_t)col*EMB);
      ap[0] = make_float4(tanhf(d*a[0]), tanhf(d*a[1]), tanhf(d*a[2]),  tanhf(d*a[3]));
      ap[1] = make_float4(tanhf(d*a[4]), tanhf(d*a[5]), tanhf(d*a[6]),  tanhf(d*a[7]));
      ap[2] = make_float4(tanhf(d*a[8]), tanhf(d*a[9]), tanhf(d*a[10]), tanhf(d*a[11]));
    } else {
      float h[12];
      #pragma unroll
      for (int k=0;k<12;k++) h[k] = tanhf(d*a[k]);
      float o[12];
      #pragma unroll
      for (int jj=0;jj<12;jj++){
        float v = bs[jj];
        #pragma unroll
        for (int k=0;k<12;k++) v = fmaf(h[k], Ws[k*EMB+jj], v);
        o[jj] = d*v;
      }
      rowstore(gout + (size_t)col*16, o);
    }
  }
}

// ---- FALLBACK (small ws): atomic scatter path ----------------------------
__global__ void k_cnt_deg(const int* __restrict__ ei, const int* __restrict__ flags,
                          int* __restrict__ cnt, int e){
  int i = blockIdx.x*blockDim.x + threadIdx.x;
  if (i >= e) return;
  atomicAdd(&cnt[ld_col(ei, e, i, flags[0])], 1);
}
__global__ void k_dinv_from_cnt(const int* __restrict__ cnt, float* __restrict__ dinv, int n){
  int i = blockIdx.x*blockDim.x + threadIdx.x;
  if (i < n) dinv[i] = rsqrtf((float)(cnt[i] + 1));
}
template<typename GT>
__global__ void k_lin_mid(const float* __restrict__ acc, const void* __restrict__ W,
                          const void* __restrict__ b, const int* __restrict__ flags,
                          const float* __restrict__ dinv,
                          GT* __restrict__ g, int n){
  __shared__ float Ws[EMB*EMB];
  __shared__ float bs[EMB];
  int t = threadIdx.x;
  int isbf = flags[1];
  if (t < EMB*EMB) Ws[t] = ldf(W, t, isbf);
  if (t < EMB)     bs[t] = ldf(b, t, isbf);
  __syncthreads();
  int i = blockIdx.x*blockDim.x + t;
  if (i >= n) return;
  float xi[EMB];
  size_t abase = (size_t)i*EMB;
  #pragma unroll
  for (int k=0;k<EMB;k++) xi[k] = tanhf(acc[abase+k]);
  float d = dinv[i];
  float o[12];
  #pragma unroll
  for (int j=0;j<EMB;j++){
    float h = bs[j];
    #pragma unroll
    for (int k=0;k<EMB;k++) h = fmaf(xi[k], Ws[k*EMB+j], h);
    o[j] = d*h;
  }
  rowstore(g + (size_t)i*16, o);
}
__global__ void k_selfinit(const float* __restrict__ g, const float* __restrict__ dinv,
                           float* __restrict__ acc, int n){
  int i = blockIdx.x*blockDim.x + threadIdx.x;
  if (i >= n) return;
  float d = dinv[i];
  float h[12]; rowload(g + (size_t)i*16, h);
  #pragma unroll
  for (int j=0;j<EMB;j++) acc[(size_t)i*EMB+j] = d*h[j];
}
__global__ void k_scatter(const int* __restrict__ ei, const int* __restrict__ flags,
                          const float* __restrict__ dinv, const float* __restrict__ g,
                          float* __restrict__ acc, int e){
  int i = blockIdx.x*blockDim.x + threadIdx.x;
  if (i >= e) return;
  int w64 = flags[0];
  int r = ld_row(ei, e, i, w64);
  int c = ld_col(ei, e, i, w64);
  float w = dinv[c];
  float h[12];
  rowload(g + (size_t)r*16, h);
  float* ap = acc + (size_t)c*EMB;
  #pragma unroll
  for (int j=0;j<EMB;j++) atomicAdd(ap+j, w*h[j]);
}

// ---- pooling + output head ----------------------------------------------
template<int DOTANH>
__global__ void __launch_bounds__(256)
k_pool(const float* __restrict__ acc, const int* __restrict__ batch,
       const int* __restrict__ flags,
       const void* __restrict__ Wout, const void* __restrict__ bout,
       void* __restrict__ out, int n){
  int g = blockIdx.x;
  int w64  = flags[0];
  int isbf = flags[1];
  __shared__ int se[2];
  __shared__ float smax[4][EMB];
  __shared__ float ssum[4][EMB];
  __shared__ float hid[2*EMB];
  if (threadIdx.x == 0){
    int lo=0, hi=n;
    while (lo<hi){ int m=(lo+hi)>>1; if (ld_batch(batch,m,w64) < g) lo=m+1; else hi=m; }
    se[0]=lo;
    int lo2=lo; hi=n;
    while (lo2<hi){ int m=(lo2+hi)>>1; if (ld_batch(batch,m,w64) < g+1) lo2=m+1; else hi=m; }
    se[1]=lo2;
  }
  __syncthreads();
  int start=se[0], end=se[1];
  float lmax[EMB], lsum[EMB];
  #pragma unroll
  for (int j=0;j<EMB;j++){ lmax[j]=-3.0e38f; lsum[j]=0.f; }
  for (int i=start+(int)threadIdx.x; i<end; i+=blockDim.x){
    size_t base=(size_t)i*EMB;
    #pragma unroll
    for (int j=0;j<EMB;j++){
      float h = DOTANH ? tanhf(acc[base+j]) : acc[base+j];
      lmax[j] = fmaxf(lmax[j], h);
      lsum[j] += h;
    }
  }
  #pragma unroll
  for (int m=32;m>=1;m>>=1){
    #pragma unroll
    for (int j=0;j<EMB;j++){
      lmax[j] = fmaxf(lmax[j], __shfl_xor(lmax[j], m, 64));
      lsum[j] += __shfl_xor(lsum[j], m, 64);
    }
  }
  int wave = threadIdx.x>>6, lane = threadIdx.x&63;
  if (lane==0){
    #pragma unroll
    for (int j=0;j<EMB;j++){ smax[wave][j]=lmax[j]; ssum[wave][j]=lsum[j]; }
  }
  __syncthreads();
  int cnt = end-start;
  if (threadIdx.x < EMB){
    int j = threadIdx.x;
    float mx=smax[0][j], sm=ssum[0][j];
    #pragma unroll
    for (int w=1;w<4;w++){ mx=fmaxf(mx,smax[w][j]); sm+=ssum[w][j]; }
    if (cnt <= 0){ mx = 0.f; sm = 0.f; }
    float mean = sm / fmaxf((float)cnt, 1.0f);
    hid[j]     = mx;
    hid[EMB+j] = mean;
    stout(out, (size_t)NG*NCLS + (size_t)g*2*EMB + j,       mx,   isbf);
    stout(out, (size_t)NG*NCLS + (size_t)g*2*EMB + EMB + j, mean, isbf);
  }
  __syncthreads();
  if (threadIdx.x < NCLS){
    int c = threadIdx.x;
    float o = ldf(bout, c, isbf);
    #pragma unroll
    for (int k=0;k<2*EMB;k++) o = fmaf(hid[k], ldf(Wout, (size_t)k*NCLS+c, isbf), o);
    stout(out, (size_t)g*NCLS + c, o, isbf);
  }
}

__global__ void k_zero_out_noflags(void* __restrict__ out, int m){
  int i = blockIdx.x*blockDim.x + threadIdx.x;
  if (i < m) ((float*)out)[i] = 0.0f;
}

// ---- build (shared by fast paths) ----------------------------------------
static void build_part(const int* ei, const void* x, int* flags, int* bcnt, int* bbase,
                       int* bcur, float* dinv, int* pairs,
                       int N, int E, int NB, hipStream_t stream){
  const int TB = 256;
  const int gc = (E + CHUNK - 1) / CHUNK;
  k_detect      <<<1, 64, 0, stream>>>(ei, (const unsigned short*)x, flags);
  k_zero_i      <<<(NB+TB-1)/TB, TB, 0, stream>>>(bcnt, NB);
  k_bkt_count   <<<gc, TB, 0, stream>>>(ei, flags, bcnt, E, NB);
  k_bkt_scan_par<<<1, 1024, 0, stream>>>(bcnt, bbase, bcur, NB);
  k_bkt_place   <<<gc, TB, 0, stream>>>(ei, flags, bcur, pairs, E, NB);
  k_deg         <<<NB, TB, 0, stream>>>(pairs, bbase, dinv, N);
}

static size_t alignup(size_t v){ return (v + 63) & ~(size_t)63; }
static size_t maxsz(size_t a, size_t b){ return a > b ? a : b; }

extern "C" void kernel_launch(void* const* d_in, const int* in_sizes, int n_in,
                              void* d_out, int out_size, void* d_ws, size_t ws_size,
                              hipStream_t stream) {
  const void* x     = d_in[0];
  const int*  ei    = (const int*)d_in[1];
  const int*  batch = (const int*)d_in[2];
  const void* W0 = d_in[3];  const void* b0 = d_in[4];
  const void* W1 = d_in[5];  const void* b1 = d_in[6];
  const void* W2 = d_in[7];  const void* b2 = d_in[8];
  const void* W3 = d_in[9];  const void* b3 = d_in[10];
  const void* Wout = d_in[11]; const void* bout = d_in[12];

  const int N = in_sizes[0] / 4;
  const int E = in_sizes[1] / 2;
  const int NB = (N + BSPAN - 1) >> BSHIFT;
  const int TB = 256;
  const int gn = (N + TB - 1) / TB;

  char* base = (char*)d_ws;

  // header: flags | dinv | bcnt | bbase | bcur | pairs (persists all layers)
  size_t o_flags  = 0;
  size_t o_dinv   = alignup(o_flags + 64);
  size_t o_bcnt   = alignup(o_dinv + (size_t)N*4);
  size_t o_bbase  = alignup(o_bcnt + (size_t)NB*4);
  size_t o_bcur   = alignup(o_bbase + ((size_t)NB+1)*4);
  size_t o_pairs  = alignup(o_bcur + (size_t)NB*4);
  size_t o_buf    = alignup(o_pairs + (size_t)E*4);

  int* flags  = (int*)(base+o_flags);
  float* dinv = (float*)(base+o_dinv);
  int* bcnt   = (int*)(base+o_bcnt);
  int* bbase  = (int*)(base+o_bbase);
  int* bcur   = (int*)(base+o_bcur);
  int* pairs  = (int*)(base+o_pairs);

  bool fast_ok = (N < (1<<19)) && (NB <= MAXNB);

  // T1: bf16 g double-buffered. acc(12N f32) aliases R0 (gA dead by then).
  {
    size_t szR0 = maxsz((size_t)N*16*2, (size_t)N*EMB*4);
    size_t o_gB = alignup(o_buf + szR0);
    size_t need = o_gB + (size_t)N*16*2;
    if (fast_ok && ws_size >= need){
      bf16*  gA  = (bf16*)(base+o_buf);
      bf16*  gB  = (bf16*)(base+o_gB);
      float* acc = (float*)(base+o_buf);
      build_part(ei, x, flags, bcnt, bbase, bcur, dinv, pairs, N, E, NB, stream);
      k_lin_first<bf16><<<gn, TB, 0, stream>>>(x, W0, b0, flags, dinv, gA, N);
      k_agg<bf16,0><<<NB, TB, 0, stream>>>(pairs, bbase, dinv, gA, W1, b1, flags, gB, (float*)0, N);
      k_agg<bf16,0><<<NB, TB, 0, stream>>>(pairs, bbase, dinv, gB, W2, b2, flags, gA, (float*)0, N);
      k_agg<bf16,0><<<NB, TB, 0, stream>>>(pairs, bbase, dinv, gA, W3, b3, flags, gB, (float*)0, N);
      k_agg<bf16,1><<<NB, TB, 0, stream>>>(pairs, bbase, dinv, gB, (const void*)0, (const void*)0, flags, (bf16*)0, acc, N);
      k_pool<0><<<NG, 256, 0, stream>>>(acc, batch, flags, Wout, bout, d_out, N);
      return;
    }
  }

  // T2: f32 g double-buffered. acc aliases gA.
  {
    size_t o_gA = o_buf;
    size_t o_gB = alignup(o_gA + (size_t)N*16*4);
    size_t need = o_gB + (size_t)N*16*4;
    if (fast_ok && ws_size >= need){
      float* gA  = (float*)(base+o_gA);
      float* gB  = (float*)(base+o_gB);
      float* acc = gA;
      build_part(ei, x, flags, bcnt, bbase, bcur, dinv, pairs, N, E, NB, stream);
      k_lin_first<float><<<gn, TB, 0, stream>>>(x, W0, b0, flags, dinv, gA, N);
      k_agg<float,0><<<NB, TB, 0, stream>>>(pairs, bbase, dinv, gA, W1, b1, flags, gB, (float*)0, N);
      k_agg<float,0><<<NB, TB, 0, stream>>>(pairs, bbase, dinv, gB, W2, b2, flags, gA, (float*)0, N);
      k_agg<float,0><<<NB, TB, 0, stream>>>(pairs, bbase, dinv, gA, W3, b3, flags, gB, (float*)0, N);
      k_agg<float,1><<<NB, TB, 0, stream>>>(pairs, bbase, dinv, gB, (const void*)0, (const void*)0, flags, (float*)0, acc, N);
      k_pool<0><<<NG, 256, 0, stream>>>(acc, batch, flags, Wout, bout, d_out, N);
      return;
    }
  }

  // T4: atomic-scatter fallback (no bucket structures)
  {
    size_t f_cnt  = alignup(o_dinv + (size_t)N*4);
    size_t f_g    = alignup(f_cnt + (size_t)N*4);
    size_t f_acc  = alignup(f_g + (size_t)N*16*4);
    size_t f_end  = f_acc + (size_t)N*EMB*4;
    const int ge = (E + TB - 1) / TB;
    int* cnt = (int*)(base+f_cnt);

    if (ws_size >= f_end){
      float* g   = (float*)(base+f_g);
      float* acc = (float*)(base+f_acc);
      k_detect  <<<1, 64, 0, stream>>>(ei, (const unsigned short*)x, flags);
      k_zero_i  <<<gn, TB, 0, stream>>>(cnt, N);
      k_cnt_deg <<<ge, TB, 0, stream>>>(ei, flags, cnt, E);
      k_dinv_from_cnt<<<gn, TB, 0, stream>>>(cnt, dinv, N);
      k_lin_first<float><<<gn, TB, 0, stream>>>(x, W0, b0, flags, dinv, g, N);
      k_selfinit <<<gn, TB, 0, stream>>>(g, dinv, acc, N);
      k_scatter  <<<ge, TB, 0, stream>>>(ei, flags, dinv, g, acc, E);
      const void* Wl[3] = {W1,W2,W3};
      const void* bl[3] = {b1,b2,b3};
      for (int l=0;l<3;l++){
        k_lin_mid<float><<<gn, TB, 0, stream>>>(acc, Wl[l], bl[l], flags, dinv, g, N);
        k_selfinit<<<gn, TB, 0, stream>>>(g, dinv, acc, N);
        k_scatter <<<ge, TB, 0, stream>>>(ei, flags, dinv, g, acc, E);
      }
      k_pool<1><<<NG, 256, 0, stream>>>(acc, batch, flags, Wout, bout, d_out, N);
    } else {
      k_zero_out_noflags<<<(out_size+255)/256, 256, 0, stream>>>(d_out, out_size);
    }
  }
}

// Round 13
// 732.840 us; speedup vs baseline: 3.1381x; 3.1381x over previous
//
#include <hip/hip_runtime.h>
#include <hip/hip_bf16.h>
#include <math.h>

typedef __hip_bfloat16 bf16;

#define EMB 12
#define NCLS 17
#define NG 1000
#define BSHIFT 9
#define BSPAN 512            // cols per bucket
#define MAXNB 1024           // max buckets (N <= 524287)
#define CHUNK 16384          // edges per block (16384 beats 4096: r7/r8 A/B)
#define EB 8                 // edge batch (MLP) in count/place
#define TSHIFT 16            // source tile = 65536 nodes
#define NTILE 8              // max tiles (N < 2^19)
#define NKEY (BSPAN*NTILE)   // 4096 sort keys in k_group

__device__ __forceinline__ float b2f(bf16 v){ return __bfloat162float(v); }

__device__ __forceinline__ unsigned short f2bf_rne(float f){
  unsigned int u = __float_as_uint(f);
  unsigned int r = (u + 0x7FFFu + ((u >> 16) & 1u)) >> 16;
  return (unsigned short)r;
}

__device__ __forceinline__ float ldf(const void* p, size_t i, int isbf){
  if (isbf) return b2f(((const bf16*)p)[i]);
  return ((const float*)p)[i];
}
__device__ __forceinline__ void stout(void* p, size_t i, float v, int isbf){
  if (isbf) ((unsigned short*)p)[i] = f2bf_rne(v);
  else      ((float*)p)[i] = v;
}

// ---- row load/store, stride 16 elements ----------------------------------
__device__ __forceinline__ void rowload(const float* p, float o[12]){
  const float4* q = (const float4*)p;
  float4 a = q[0], b = q[1], c = q[2];
  o[0]=a.x;o[1]=a.y;o[2]=a.z;o[3]=a.w;o[4]=b.x;o[5]=b.y;o[6]=b.z;o[7]=b.w;
  o[8]=c.x;o[9]=c.y;o[10]=c.z;o[11]=c.w;
}
__device__ __forceinline__ void rowload(const bf16* p, float o[12]){
  const uint4* q = (const uint4*)p;       // 32B row, 16B aligned
  uint4 u0 = q[0];
  uint2 u1 = *(const uint2*)(q+1);
  o[0] =__uint_as_float(u0.x<<16); o[1] =__uint_as_float(u0.x&0xFFFF0000u);
  o[2] =__uint_as_float(u0.y<<16); o[3] =__uint_as_float(u0.y&0xFFFF0000u);
  o[4] =__uint_as_float(u0.z<<16); o[5] =__uint_as_float(u0.z&0xFFFF0000u);
  o[6] =__uint_as_float(u0.w<<16); o[7] =__uint_as_float(u0.w&0xFFFF0000u);
  o[8] =__uint_as_float(u1.x<<16); o[9] =__uint_as_float(u1.x&0xFFFF0000u);
  o[10]=__uint_as_float(u1.y<<16); o[11]=__uint_as_float(u1.y&0xFFFF0000u);
}
__device__ __forceinline__ void rowstore(float* p, const float o[12]){
  float4* q = (float4*)p;
  q[0] = make_float4(o[0],o[1],o[2],o[3]);
  q[1] = make_float4(o[4],o[5],o[6],o[7]);
  q[2] = make_float4(o[8],o[9],o[10],o[11]);
}
__device__ __forceinline__ void rowstore(bf16* p, const float o[12]){
  unsigned int u[6];
  #pragma unroll
  for (int k=0;k<6;k++)
    u[k] = (unsigned int)f2bf_rne(o[2*k]) | ((unsigned int)f2bf_rne(o[2*k+1])<<16);
  uint2* q = (uint2*)p;
  q[0] = make_uint2(u[0],u[1]);
  q[1] = make_uint2(u[2],u[3]);
  q[2] = make_uint2(u[4],u[5]);
}

// ---- runtime dtype detection ---------------------------------------------
__global__ void k_detect(const int* __restrict__ ei, const unsigned short* __restrict__ xh,
                         int* __restrict__ flags){
  if (blockIdx.x==0 && threadIdx.x==0){
    int z = 1;
    for (int k=1; k<32; k+=2) z &= (ei[k]==0);
    flags[0] = z;
    int hits = 0;
    for (int k=0; k<32; k+=2){
      int e = (xh[k] >> 7) & 0xFF;
      if (e >= 100 && e <= 140) hits++;
    }
    flags[1] = (hits >= 12) ? 1 : 0;
  }
}
__device__ __forceinline__ int ld_row(const int* ei, long long E, long long i, int w64){
  return w64 ? ei[2*i] : ei[i];
}
__device__ __forceinline__ int ld_col(const int* ei, long long E, long long i, int w64){
  return w64 ? ei[2*E + 2*i] : ei[E + i];
}
__device__ __forceinline__ int ld_batch(const int* b, long long i, int w64){
  return w64 ? b[2*i] : b[i];
}

// ---- bucketed CSR build (no per-edge global atomics) ---------------------
__global__ void k_zero_i(int* __restrict__ p, int n){
  int i = blockIdx.x*blockDim.x + threadIdx.x;
  if (i < n) p[i] = 0;
}
// Pass A: per-block LDS histogram; writes per-block counts (bofs) + totals.
__global__ void __launch_bounds__(256)
k_bkt_count(const int* __restrict__ ei, const int* __restrict__ flags,
            int* __restrict__ bcnt, int* __restrict__ bofs, int E, int NB){
  __shared__ int h[MAXNB];
  int t = threadIdx.x;
  for (int j=t; j<NB; j+=256) h[j] = 0;
  __syncthreads();
  int w64 = flags[0];
  long long base = (long long)blockIdx.x * CHUNK;
  for (int k0=0; k0<CHUNK; k0+=256*EB){
    int c[EB]; bool v[EB];
    #pragma unroll
    for (int u=0;u<EB;u++){
      long long i = base + k0 + u*256 + t;
      v[u] = (i < E);
      c[u] = v[u] ? ld_col(ei, E, i, w64) : 0;
    }
    #pragma unroll
    for (int u=0;u<EB;u++) if (v[u]) atomicAdd(&h[c[u]>>BSHIFT], 1);
  }
  __syncthreads();
  size_t rowb = (size_t)blockIdx.x * NB;
  for (int j=t; j<NB; j+=256){
    int c = h[j];
    bofs[rowb + j] = c;
    if (c > 0) atomicAdd(&bcnt[j], c);
  }
}
// bucket-total scan (single block)
__global__ void __launch_bounds__(1024)
k_bkt_scan_par(const int* __restrict__ bcnt, int* __restrict__ bbase,
               int* __restrict__ rowstart, int NB, int N){
  __shared__ int s[1024];
  int t = threadIdx.x;
  int v = (t < NB) ? bcnt[t] : 0;
  s[t] = v;
  __syncthreads();
  for (int off=1; off<1024; off<<=1){
    int add = (t >= off) ? s[t-off] : 0;
    __syncthreads();
    s[t] += add;
    __syncthreads();
  }
  if (t < NB) bbase[t] = s[t] - v;
  if (t == 1023){
    bbase[NB]   = s[1023];
    rowstart[N] = s[1023];
  }
}
// column scan: bofs[i][j] -> exact placement base for (block i, bucket j)
__global__ void __launch_bounds__(256)
k_colscan(int* __restrict__ bofs, const int* __restrict__ bbase, int NB, int GC){
  __shared__ int part[256];
  int j = blockIdx.x, t = threadIdx.x;
  int K = (GC + 255) / 256;
  int beg = t*K, end = beg+K < GC ? beg+K : GC;
  int s = 0;
  for (int i=beg; i<end; i++) s += bofs[(size_t)i*NB + j];
  part[t] = s;
  __syncthreads();
  for (int off=1; off<256; off<<=1){
    int add = (t >= off) ? part[t-off] : 0;
    __syncthreads();
    part[t] += add;
    __syncthreads();
  }
  int run = bbase[j] + part[t] - s;
  for (int i=beg; i<end; i++){
    size_t idx = (size_t)i*NB + j;
    int v = bofs[idx];
    bofs[idx] = run;
    run += v;
  }
}
// Pass C: place packed (coloff<<22 | tile<<19 | row), single streaming pass.
__global__ void __launch_bounds__(256)
k_bkt_place(const int* __restrict__ ei, const int* __restrict__ flags,
            const int* __restrict__ bofs, int* __restrict__ pairs, int E, int NB){
  __shared__ int h[MAXNB];
  int t = threadIdx.x;
  size_t rowb = (size_t)blockIdx.x * NB;
  for (int j=t; j<NB; j+=256) h[j] = bofs[rowb + j];
  __syncthreads();
  int w64 = flags[0];
  long long base = (long long)blockIdx.x * CHUNK;
  for (int k0=0; k0<CHUNK; k0+=256*EB){
    int r[EB], c[EB]; bool v[EB];
    #pragma unroll
    for (int u=0;u<EB;u++){
      long long i = base + k0 + u*256 + t;
      v[u] = (i < E);
      r[u] = v[u] ? ld_row(ei, E, i, w64) : 0;
      c[u] = v[u] ? ld_col(ei, E, i, w64) : 0;
    }
    int pos[EB];
    #pragma unroll
    for (int u=0;u<EB;u++) pos[u] = v[u] ? atomicAdd(&h[c[u]>>BSHIFT], 1) : 0;
    #pragma unroll
    for (int u=0;u<EB;u++)
      if (v[u]) pairs[pos[u]] = r[u] | ((r[u]>>TSHIFT)<<19) | ((c[u] & (BSPAN-1)) << 22);
  }
}
// Pass D: one block per bucket — sort by (col, src-tile), 4096-key LDS scan.
__global__ void __launch_bounds__(256)
k_group(const int* __restrict__ pairs, const int* __restrict__ bbase,
        int* __restrict__ rowstart, float* __restrict__ dinv,
        int* __restrict__ src, int N){
  __shared__ int cnt[NKEY];   // 16 KB
  __shared__ int cur[NKEY];   // 16 KB
  __shared__ int part[256];
  int b = blockIdx.x, t = threadIdx.x;
  int lo = bbase[b], hi = bbase[b+1];
  #pragma unroll
  for (int u=0;u<NKEY/256;u++) cnt[u*256+t] = 0;
  __syncthreads();
  {
    int p = lo + t;
    for (; p + 3*256 < hi; p += 4*256){
      int k0=pairs[p]>>19, k1=pairs[p+256]>>19, k2=pairs[p+512]>>19, k3=pairs[p+768]>>19;
      atomicAdd(&cnt[k0],1); atomicAdd(&cnt[k1],1);
      atomicAdd(&cnt[k2],1); atomicAdd(&cnt[k3],1);
    }
    for (; p < hi; p += 256) atomicAdd(&cnt[pairs[p]>>19],1);
  }
  __syncthreads();
  int loc[16]; int s = 0;
  #pragma unroll
  for (int u=0;u<16;u++){ loc[u] = cnt[t*16+u]; s += loc[u]; }
  part[t] = s;
  __syncthreads();
  for (int off=1; off<256; off<<=1){
    int add = (t >= off) ? part[t-off] : 0;
    __syncthreads();
    part[t] += add;
    __syncthreads();
  }
  int run = lo + part[t] - s;
  #pragma unroll
  for (int u=0;u<16;u++){ cur[t*16+u] = run; run += loc[u]; }
  __syncthreads();
  int col0 = b << BSHIFT;
  #pragma unroll
  for (int u=0;u<2;u++){
    int j = 2*t + u;
    int colg = col0 + j;
    if (colg < N){
      int cb = cur[j*NTILE];
      int ce = (j == BSPAN-1) ? hi : cur[(j+1)*NTILE];
      rowstart[colg] = cb;
      dinv[colg] = rsqrtf((float)(ce - cb) + 1.0f);
    }
  }
  __syncthreads();
  {
    int p = lo + t;
    for (; p + 3*256 < hi; p += 4*256){
      int pk0=pairs[p], pk1=pairs[p+256], pk2=pairs[p+512], pk3=pairs[p+768];
      int q0 = atomicAdd(&cur[pk0>>19], 1);
      int q1 = atomicAdd(&cur[pk1>>19], 1);
      int q2 = atomicAdd(&cur[pk2>>19], 1);
      int q3 = atomicAdd(&cur[pk3>>19], 1);
      src[q0] = pk0 & 0x7FFFF; src[q1] = pk1 & 0x7FFFF;
      src[q2] = pk2 & 0x7FFFF; src[q3] = pk3 & 0x7FFFF;
    }
    for (; p < hi; p += 256){
      int pk = pairs[p];
      int q = atomicAdd(&cur[pk>>19], 1);
      src[q] = pk & 0x7FFFF;
    }
  }
}

// ---- lin-first: g = dinv * (x @ W0 + b0), row stride 16 ------------------
template<typename GT>
__global__ void k_lin_first(const void* __restrict__ x, const void* __restrict__ W,
                            const void* __restrict__ b, const int* __restrict__ flags,
                            const float* __restrict__ dinv,
                            GT* __restrict__ g, int n){
  __shared__ float Ws[4*EMB];
  __shared__ float bs[EMB];
  int t = threadIdx.x;
  int isbf = flags[1];
  if (t < 4*EMB) Ws[t] = ldf(W, t, isbf);
  if (t < EMB)   bs[t] = ldf(b, t, isbf);
  __syncthreads();
  int i = blockIdx.x*blockDim.x + t;
  if (i >= n) return;
  float xi[4];
  #pragma unroll
  for (int k=0;k<4;k++) xi[k] = ldf(x, (size_t)i*4+k, isbf);
  float d = dinv[i];
  float o[12];
  #pragma unroll
  for (int j=0;j<EMB;j++){
    float h = bs[j];
    #pragma unroll
    for (int k=0;k<4;k++) h = fmaf(xi[k], Ws[k*EMB+j], h);
    o[j] = d*h;
  }
  rowstore(g + (size_t)i*16, o);
}

// ---- lin-mid (unfused path) ----------------------------------------------
template<typename GT>
__global__ void k_lin_mid(const float* __restrict__ acc, const void* __restrict__ W,
                          const void* __restrict__ b, const int* __restrict__ flags,
                          const float* __restrict__ dinv,
                          GT* __restrict__ g, int n){
  __shared__ float Ws[EMB*EMB];
  __shared__ float bs[EMB];
  int t = threadIdx.x;
  int isbf = flags[1];
  if (t < EMB*EMB) Ws[t] = ldf(W, t, isbf);
  if (t < EMB)     bs[t] = ldf(b, t, isbf);
  __syncthreads();
  int i = blockIdx.x*blockDim.x + t;
  if (i >= n) return;
  float xi[EMB];
  size_t abase = (size_t)i*EMB;
  #pragma unroll
  for (int k=0;k<EMB;k++) xi[k] = tanhf(acc[abase+k]);
  float d = dinv[i];
  float o[12];
  #pragma unroll
  for (int j=0;j<EMB;j++){
    float h = bs[j];
    #pragma unroll
    for (int k=0;k<EMB;k++) h = fmaf(xi[k], Ws[k*EMB+j], h);
    o[j] = d*h;
  }
  rowstore(g + (size_t)i*16, o);
}

// ---- edge-sum: a[] = g[i] + sum_{edges} g[src], 4x unrolled --------------
// src is tile-sorted per col (k_group) -> implicit L2 temporal locality.
template<typename GT>
__device__ __forceinline__ void edge_sum16(const GT* __restrict__ g,
                                           const int* __restrict__ rowstart,
                                           const int* __restrict__ src,
                                           int i, float a[12]){
  rowload(g + (size_t)i*16, a);
  int s = rowstart[i], e = rowstart[i+1];
  int p = s;
  for (; p+4 <= e; p += 4){
    int r0 = src[p], r1 = src[p+1], r2 = src[p+2], r3 = src[p+3];
    float h0[12], h1[12], h2[12], h3[12];
    rowload(g + (size_t)r0*16, h0);
    rowload(g + (size_t)r1*16, h1);
    rowload(g + (size_t)r2*16, h2);
    rowload(g + (size_t)r3*16, h3);
    #pragma unroll
    for (int j=0;j<12;j++) a[j] += (h0[j]+h1[j]) + (h2[j]+h3[j]);
  }
  for (; p < e; ++p){
    int r = src[p];
    float h[12];
    rowload(g + (size_t)r*16, h);
    #pragma unroll
    for (int j=0;j<12;j++) a[j] += h[j];
  }
}

// ---- fused gather: conv -> tanh -> @W+b -> *dinv -> g_next ---------------
template<typename GT>
__global__ void __launch_bounds__(256)
k_gather_fused(const int* __restrict__ rowstart, const int* __restrict__ src,
               const float* __restrict__ dinv, const GT* __restrict__ gin,
               const void* __restrict__ W, const void* __restrict__ b,
               const int* __restrict__ flags, GT* __restrict__ gout, int n){
  __shared__ float Ws[EMB*EMB];
  __shared__ float bs[EMB];
  int t = threadIdx.x;
  int isbf = flags[1];
  if (t < EMB*EMB) Ws[t] = ldf(W, t, isbf);
  if (t < EMB)     bs[t] = ldf(b, t, isbf);
  __syncthreads();
  int i = blockIdx.x*blockDim.x + t;
  if (i >= n) return;
  float a[12];
  edge_sum16<GT>(gin, rowstart, src, i, a);
  float d = dinv[i];
  float h[12];
  #pragma unroll
  for (int k=0;k<12;k++) h[k] = tanhf(d*a[k]);
  float o[12];
  #pragma unroll
  for (int j=0;j<12;j++){
    float v = bs[j];
    #pragma unroll
    for (int k=0;k<12;k++) v = fmaf(h[k], Ws[k*EMB+j], v);
    o[j] = d*v;
  }
  rowstore(gout + (size_t)i*16, o);
}

// ---- final gather: conv -> tanh -> acc (f32, stride 12) ------------------
template<typename GT>
__global__ void __launch_bounds__(256)
k_gather_tanh(const int* __restrict__ rowstart, const int* __restrict__ src,
              const float* __restrict__ dinv, const GT* __restrict__ g,
              float* __restrict__ acc, int n){
  int i = blockIdx.x*blockDim.x + threadIdx.x;
  if (i >= n) return;
  float a[12];
  edge_sum16<GT>(g, rowstart, src, i, a);
  float d = dinv[i];
  float4* ap = (float4*)(acc + (size_t)i*EMB);
  ap[0] = make_float4(tanhf(d*a[0]), tanhf(d*a[1]), tanhf(d*a[2]),  tanhf(d*a[3]));
  ap[1] = make_float4(tanhf(d*a[4]), tanhf(d*a[5]), tanhf(d*a[6]),  tanhf(d*a[7]));
  ap[2] = make_float4(tanhf(d*a[8]), tanhf(d*a[9]), tanhf(d*a[10]), tanhf(d*a[11]));
}

// ---- unfused gather: acc[i] = dinv[i] * a[] ------------------------------
template<typename GT>
__global__ void __launch_bounds__(256)
k_gather_pm(const int* __restrict__ rowstart, const int* __restrict__ src,
            const float* __restrict__ dinv, const GT* __restrict__ g,
            float* __restrict__ acc, int n){
  int i = blockIdx.x*blockDim.x + threadIdx.x;
  if (i >= n) return;
  float a[12];
  edge_sum16<GT>(g, rowstart, src, i, a);
  float d = dinv[i];
  float4* ap = (float4*)(acc + (size_t)i*EMB);
  ap[0] = make_float4(d*a[0], d*a[1], d*a[2],  d*a[3]);
  ap[1] = make_float4(d*a[4], d*a[5], d*a[6],  d*a[7]);
  ap[2] = make_float4(d*a[8], d*a[9], d*a[10], d*a[11]);
}

// ---- FALLBACK (small ws): atomic scatter path ----------------------------
__global__ void k_cnt_deg(const int* __restrict__ ei, const int* __restrict__ flags,
                          int* __restrict__ cnt, int e){
  int i = blockIdx.x*blockDim.x + threadIdx.x;
  if (i >= e) return;
  atomicAdd(&cnt[ld_col(ei, e, i, flags[0])], 1);
}
__global__ void k_dinv_from_cnt(const int* __restrict__ cnt, float* __restrict__ dinv, int n){
  int i = blockIdx.x*blockDim.x + threadIdx.x;
  if (i < n) dinv[i] = rsqrtf((float)(cnt[i] + 1));
}
__global__ void k_selfinit(const float* __restrict__ g, const float* __restrict__ dinv,
                           float* __restrict__ acc, int n){
  int i = blockIdx.x*blockDim.x + threadIdx.x;
  if (i >= n) return;
  float d = dinv[i];
  float h[12]; rowload(g + (size_t)i*16, h);
  #pragma unroll
  for (int j=0;j<EMB;j++) acc[(size_t)i*EMB+j] = d*h[j];
}
__global__ void k_scatter(const int* __restrict__ ei, const int* __restrict__ flags,
                          const float* __restrict__ dinv, const float* __restrict__ g,
                          float* __restrict__ acc, int e){
  int i = blockIdx.x*blockDim.x + threadIdx.x;
  if (i >= e) return;
  int w64 = flags[0];
  int r = ld_row(ei, e, i, w64);
  int c = ld_col(ei, e, i, w64);
  float w = dinv[c];
  float h[12];
  rowload(g + (size_t)r*16, h);
  float* ap = acc + (size_t)c*EMB;
  #pragma unroll
  for (int j=0;j<EMB;j++) atomicAdd(ap+j, w*h[j]);
}

// ---- pooling + output head ----------------------------------------------
template<int DOTANH>
__global__ void __launch_bounds__(256)
k_pool(const float* __restrict__ acc, const int* __restrict__ batch,
       const int* __restrict__ flags,
       const void* __restrict__ Wout, const void* __restrict__ bout,
       void* __restrict__ out, int n){
  int g = blockIdx.x;
  int w64  = flags[0];
  int isbf = flags[1];
  __shared__ int se[2];
  __shared__ float smax[4][EMB];
  __shared__ float ssum[4][EMB];
  __shared__ float hid[2*EMB];
  if (threadIdx.x == 0){
    int lo=0, hi=n;
    while (lo<hi){ int m=(lo+hi)>>1; if (ld_batch(batch,m,w64) < g) lo=m+1; else hi=m; }
    se[0]=lo;
    int lo2=lo; hi=n;
    while (lo2<hi){ int m=(lo2+hi)>>1; if (ld_batch(batch,m,w64) < g+1) lo2=m+1; else hi=m; }
    se[1]=lo2;
  }
  __syncthreads();
  int start=se[0], end=se[1];
  float lmax[EMB], lsum[EMB];
  #pragma unroll
  for (int j=0;j<EMB;j++){ lmax[j]=-3.0e38f; lsum[j]=0.f; }
  for (int i=start+(int)threadIdx.x; i<end; i+=blockDim.x){
    size_t base=(size_t)i*EMB;
    #pragma unroll
    for (int j=0;j<EMB;j++){
      float h = DOTANH ? tanhf(acc[base+j]) : acc[base+j];
      lmax[j] = fmaxf(lmax[j], h);
      lsum[j] += h;
    }
  }
  #pragma unroll
  for (int m=32;m>=1;m>>=1){
    #pragma unroll
    for (int j=0;j<EMB;j++){
      lmax[j] = fmaxf(lmax[j], __shfl_xor(lmax[j], m, 64));
      lsum[j] += __shfl_xor(lsum[j], m, 64);
    }
  }
  int wave = threadIdx.x>>6, lane = threadIdx.x&63;
  if (lane==0){
    #pragma unroll
    for (int j=0;j<EMB;j++){ smax[wave][j]=lmax[j]; ssum[wave][j]=lsum[j]; }
  }
  __syncthreads();
  int cnt = end-start;
  if (threadIdx.x < EMB){
    int j = threadIdx.x;
    float mx=smax[0][j], sm=ssum[0][j];
    #pragma unroll
    for (int w=1;w<4;w++){ mx=fmaxf(mx,smax[w][j]); sm+=ssum[w][j]; }
    if (cnt <= 0){ mx = 0.f; sm = 0.f; }
    float mean = sm / fmaxf((float)cnt, 1.0f);
    hid[j]     = mx;
    hid[EMB+j] = mean;
    stout(out, (size_t)NG*NCLS + (size_t)g*2*EMB + j,       mx,   isbf);
    stout(out, (size_t)NG*NCLS + (size_t)g*2*EMB + EMB + j, mean, isbf);
  }
  __syncthreads();
  if (threadIdx.x < NCLS){
    int c = threadIdx.x;
    float o = ldf(bout, c, isbf);
    #pragma unroll
    for (int k=0;k<2*EMB;k++) o = fmaf(hid[k], ldf(Wout, (size_t)k*NCLS+c, isbf), o);
    stout(out, (size_t)g*NCLS + c, o, isbf);
  }
}

__global__ void k_zero_out_noflags(void* __restrict__ out, int m){
  int i = blockIdx.x*blockDim.x + threadIdx.x;
  if (i < m) ((float*)out)[i] = 0.0f;
}

// ---- CSR build (shared) --------------------------------------------------
static void build_csr(const int* ei, const void* x, int* flags, int* bcnt, int* bbase,
                      int* bofs, int* rowstart, float* dinv, int* src, int* pairs,
                      int N, int E, int NB, hipStream_t stream){
  const int TB = 256;
  const int gc = (E + CHUNK - 1) / CHUNK;
  k_detect      <<<1, 64, 0, stream>>>(ei, (const unsigned short*)x, flags);
  k_zero_i      <<<(NB+TB-1)/TB, TB, 0, stream>>>(bcnt, NB);
  k_bkt_count   <<<gc, TB, 0, stream>>>(ei, flags, bcnt, bofs, E, NB);
  k_bkt_scan_par<<<1, 1024, 0, stream>>>(bcnt, bbase, rowstart, NB, N);
  k_colscan     <<<NB, TB, 0, stream>>>(bofs, bbase, NB, gc);
  k_bkt_place   <<<gc, TB, 0, stream>>>(ei, flags, bofs, pairs, E, NB);
  k_group       <<<NB, TB, 0, stream>>>(pairs, bbase, rowstart, dinv, src, N);
}

static size_t alignup(size_t v){ return (v + 63) & ~(size_t)63; }
static size_t maxsz(size_t a, size_t b){ return a > b ? a : b; }

extern "C" void kernel_launch(void* const* d_in, const int* in_sizes, int n_in,
                              void* d_out, int out_size, void* d_ws, size_t ws_size,
                              hipStream_t stream) {
  const void* x     = d_in[0];
  const int*  ei    = (const int*)d_in[1];
  const int*  batch = (const int*)d_in[2];
  const void* W0 = d_in[3];  const void* b0 = d_in[4];
  const void* W1 = d_in[5];  const void* b1 = d_in[6];
  const void* W2 = d_in[7];  const void* b2 = d_in[8];
  const void* W3 = d_in[9];  const void* b3 = d_in[10];
  const void* Wout = d_in[11]; const void* bout = d_in[12];

  const int N = in_sizes[0] / 4;
  const int E = in_sizes[1] / 2;
  const int NB = (N + BSPAN - 1) >> BSHIFT;
  const int GC = (E + CHUNK - 1) / CHUNK;
  const int TB = 256;
  const int gn = (N + TB - 1) / TB;

  char* base = (char*)d_ws;

  size_t o_flags  = 0;
  size_t o_dinv   = alignup(o_flags + 64);
  size_t o_bcnt   = alignup(o_dinv + (size_t)N*4);
  size_t o_bbase  = alignup(o_bcnt + (size_t)NB*4);
  size_t o_bofs   = alignup(o_bbase + ((size_t)NB+1)*4);
  size_t o_rowst  = alignup(o_bofs + (size_t)GC*NB*4);
  size_t o_src    = alignup(o_rowst + ((size_t)N+1)*4);
  size_t o_buf    = alignup(o_src + (size_t)E*4);     // pairs aliases from here

  int* flags  = (int*)(base+o_flags);
  float* dinv = (float*)(base+o_dinv);
  int* bcnt   = (int*)(base+o_bcnt);
  int* bbase  = (int*)(base+o_bbase);
  int* bofs   = (int*)(base+o_bofs);
  int* rowst  = (int*)(base+o_rowst);
  int* src    = (int*)(base+o_src);
  int* pairs  = (int*)(base+o_buf);

  bool fast_ok = (N < (1<<19)) && (NB <= MAXNB);

  // T1: fused, bf16 g double-buffered. acc aliases R0.
  {
    size_t szR0 = maxsz((size_t)N*16*2, (size_t)N*EMB*4);
    size_t o_gB = alignup(o_buf + szR0);
    size_t need = o_gB + (size_t)N*16*2;
    bool pairs_fit = (size_t)E*4 <= need - o_buf;
    if (fast_ok && pairs_fit && ws_size >= need){
      bf16*  gA  = (bf16*)(base+o_buf);
      bf16*  gB  = (bf16*)(base+o_gB);
      float* acc = (float*)(base+o_buf);
      build_csr(ei, x, flags, bcnt, bbase, bofs, rowst, dinv, src, pairs, N, E, NB, stream);
      k_lin_first<bf16><<<gn, TB, 0, stream>>>(x, W0, b0, flags, dinv, gA, N);
      k_gather_fused<bf16><<<gn, TB, 0, stream>>>(rowst, src, dinv, gA, W1, b1, flags, gB, N);
      k_gather_fused<bf16><<<gn, TB, 0, stream>>>(rowst, src, dinv, gB, W2, b2, flags, gA, N);
      k_gather_fused<bf16><<<gn, TB, 0, stream>>>(rowst, src, dinv, gA, W3, b3, flags, gB, N);
      k_gather_tanh<bf16><<<gn, TB, 0, stream>>>(rowst, src, dinv, gB, acc, N);
      k_pool<0><<<NG, 256, 0, stream>>>(acc, batch, flags, Wout, bout, d_out, N);
      return;
    }
  }

  // T2: fused, f32 g double-buffered. acc aliases gA.
  {
    size_t o_gA = o_buf;
    size_t o_gB = alignup(o_gA + (size_t)N*16*4);
    size_t need = o_gB + (size_t)N*16*4;
    bool pairs_fit = (size_t)E*4 <= need - o_buf;
    if (fast_ok && pairs_fit && ws_size >= need){
      float* gA  = (float*)(base+o_gA);
      float* gB  = (float*)(base+o_gB);
      float* acc = gA;
      build_csr(ei, x, flags, bcnt, bbase, bofs, rowst, dinv, src, pairs, N, E, NB, stream);
      k_lin_first<float><<<gn, TB, 0, stream>>>(x, W0, b0, flags, dinv, gA, N);
      k_gather_fused<float><<<gn, TB, 0, stream>>>(rowst, src, dinv, gA, W1, b1, flags, gB, N);
      k_gather_fused<float><<<gn, TB, 0, stream>>>(rowst, src, dinv, gB, W2, b2, flags, gA, N);
      k_gather_fused<float><<<gn, TB, 0, stream>>>(rowst, src, dinv, gA, W3, b3, flags, gB, N);
      k_gather_tanh<float><<<gn, TB, 0, stream>>>(rowst, src, dinv, gB, acc, N);
      k_pool<0><<<NG, 256, 0, stream>>>(acc, batch, flags, Wout, bout, d_out, N);
      return;
    }
  }

  // T3: unfused f32: acc(12N f32) | g(16N f32)
  {
    size_t o_acc = o_buf;
    size_t o_g   = alignup(o_acc + (size_t)N*EMB*4);
    size_t need  = o_g + (size_t)N*16*4;
    bool pairs_fit = (size_t)E*4 <= need - o_buf;
    if (fast_ok && pairs_fit && ws_size >= need){
      float* acc = (float*)(base+o_acc);
      float* g   = (float*)(base+o_g);
      build_csr(ei, x, flags, bcnt, bbase, bofs, rowst, dinv, src, pairs, N, E, NB, stream);
      k_lin_first<float><<<gn, TB, 0, stream>>>(x, W0, b0, flags, dinv, g, N);
      k_gather_pm<float><<<gn, TB, 0, stream>>>(rowst, src, dinv, g, acc, N);
      const void* Wl[3] = {W1,W2,W3};
      const void* bl[3] = {b1,b2,b3};
      for (int l=0;l<3;l++){
        k_lin_mid<float><<<gn, TB, 0, stream>>>(acc, Wl[l], bl[l], flags, dinv, g, N);
        k_gather_pm<float><<<gn, TB, 0, stream>>>(rowst, src, dinv, g, acc, N);
      }
      k_pool<1><<<NG, 256, 0, stream>>>(acc, batch, flags, Wout, bout, d_out, N);
      return;
    }
  }

  // T4: atomic-scatter fallback
  {
    size_t f_cnt  = alignup(o_dinv + (size_t)N*4);
    size_t f_g    = alignup(f_cnt + (size_t)N*4);
    size_t f_acc  = alignup(f_g + (size_t)N*16*4);
    size_t f_end  = f_acc + (size_t)N*EMB*4;
    const int ge = (E + TB - 1) / TB;
    int* cnt = (int*)(base+f_cnt);

    if (ws_size >= f_end){
      float* g   = (float*)(base+f_g);
      float* acc = (float*)(base+f_acc);
      k_detect  <<<1, 64, 0, stream>>>(ei, (const unsigned short*)x, flags);
      k_zero_i  <<<gn, TB, 0, stream>>>(cnt, N);
      k_cnt_deg <<<ge, TB, 0, stream>>>(ei, flags, cnt, E);
      k_dinv_from_cnt<<<gn, TB, 0, stream>>>(cnt, dinv, N);
      k_lin_first<float><<<gn, TB, 0, stream>>>(x, W0, b0, flags, dinv, g, N);
      k_selfinit <<<gn, TB, 0, stream>>>(g, dinv, acc, N);
      k_scatter  <<<ge, TB, 0, stream>>>(ei, flags, dinv, g, acc, E);
      const void* Wl[3] = {W1,W2,W3};
      const void* bl[3] = {b1,b2,b3};
      for (int l=0;l<3;l++){
        k_lin_mid<float><<<gn, TB, 0, stream>>>(acc, Wl[l], bl[l], flags, dinv, g, N);
        k_selfinit<<<gn, TB, 0, stream>>>(g, dinv, acc, N);
        k_scatter <<<ge, TB, 0, stream>>>(ei, flags, dinv, g, acc, E);
      }
      k_pool<1><<<NG, 256, 0, stream>>>(acc, batch, flags, Wout, bout, d_out, N);
    } else {
      k_zero_out_noflags<<<(out_size+255)/256, 256, 0, stream>>>(d_out, out_size);
    }
  }
}